// Round 10
// baseline (488.628 us; speedup 1.0000x reference)
//
#include <hip/hip_runtime.h>

#define NQ 8
#define KCODES 1024
#define D 64
#define CHUNK 64
#define NCHUNK 16
#define TPB 512
#define TOKPB 128            // tokens per block = 4 groups x 32
#define BIAS 96.0f
#define STAGE_I4 1040        // 1024 plane int4s + 16 csqh int4s (16640 B per buffer)

using short8 = __attribute__((ext_vector_type(8))) short;
using f32x4  = __attribute__((ext_vector_type(4))) float;

#define GLOBAL_AS __attribute__((address_space(1)))
#define LDS_AS    __attribute__((address_space(3)))

static __device__ __forceinline__ unsigned bf16_rne_bits(float f) {
    unsigned u = __float_as_uint(f);
    return (u + 0x7fffu + ((u >> 16) & 1u)) >> 16;   // bf16 RNE bit pattern
}
static __device__ __forceinline__ unsigned umn(unsigned a, unsigned b) { return a < b ? a : b; }
static __device__ __forceinline__ unsigned umx(unsigned a, unsigned b) { return a > b ? a : b; }
static __device__ __forceinline__ unsigned umed3(unsigned a, unsigned b, unsigned c) {
    return umx(umn(a, b), umn(umx(a, b), c));
}

// ---------------- prologue 1: split NEGATED codebook into bf16 hi/lo granules ----------------
// ws_cb layout: [q][ch16][plane16][code64], plane = term*8 + kt*4 + g. Stores -c.
__global__ __launch_bounds__(256) void prep_cb(const float* __restrict__ cb,
                                               int4* __restrict__ ws_cb) {
    int id = blockIdx.x * 256 + threadIdx.x;       // 0 .. 131071
    int n_rel = id & 63;
    int plane = (id >> 6) & 15;
    int ch    = (id >> 10) & 15;
    int q     = id >> 14;
    int g = plane & 3, kt = (plane >> 2) & 1, term = plane >> 3;
    int n = ch * CHUNK + n_rel;
    const float* src = cb + ((size_t)(q * KCODES + n)) * D + kt * 32 + g * 8;
    union { short s[8]; int4 v; } u;
    #pragma unroll
    for (int j = 0; j < 8; ++j) {
        float f = -src[j];                         // NEGATED
        unsigned hb = bf16_rne_bits(f);
        if (term == 0) {
            u.s[j] = (short)hb;
        } else {
            float lo = f - __uint_as_float(hb << 16);
            u.s[j] = (short)bf16_rne_bits(lo);
        }
    }
    ws_cb[id] = u.v;
}

// ---------------- prologue 2: c_sq exact (refine) + seed (csq/2 + BIAS, approx) ----------------
__global__ __launch_bounds__(256) void prep_csq(const float* __restrict__ cb,
                                                float* __restrict__ ws_csq,
                                                float* __restrict__ ws_csqh) {
    int id = blockIdx.x * 256 + threadIdx.x;       // 0 .. 8191
    const float* c = cb + (size_t)id * D;
    float s0 = 0.f, s1 = 0.f, s2 = 0.f, s3 = 0.f;
    #pragma unroll
    for (int j = 0; j < 16; ++j) {
        s0 = fmaf(c[4*j+0], c[4*j+0], s0);
        s1 = fmaf(c[4*j+1], c[4*j+1], s1);
        s2 = fmaf(c[4*j+2], c[4*j+2], s2);
        s3 = fmaf(c[4*j+3], c[4*j+3], s3);
    }
    float cs = (s0 + s1) + (s2 + s3);
    ws_csq[id]  = cs;                // exact, refine comparator (bit-identical to r3..r9)
    ws_csqh[id] = 0.5f * cs + BIAS;  // approx seed: acc = seed - dot (always > 0)
}

// ---------------- main kernel ----------------
// 8 waves = 4 token-groups x 2 code-halves. Double-buffered chunk staging:
// per iteration: barrier (cheap drain) -> issue DMA for next chunk -> compute current.
__global__ __launch_bounds__(TPB, 3) void rvq_mfma(
    const float* __restrict__ x,
    const float* __restrict__ cb,
    const int4* __restrict__ ws_cb,
    const float* __restrict__ ws_csq,
    float* __restrict__ out)
{
    __shared__ __align__(16) int4  lds_stage[2][STAGE_I4];   // 33280 B (planes + csqh)
    __shared__ __align__(16) float lds_resid[TOKPB * 68];    // 34816 B persistent residual
    __shared__ unsigned lds_cand[2][TOKPB * 3];              // 3072 B packed top-3 per half
    __shared__ int      lds_pick[TOKPB];                     // 512 B

    const int tid   = threadIdx.x;
    const int lane  = tid & 63;
    const int wave  = tid >> 6;          // 0..7
    const int group = wave >> 1;         // 0..3 (token group of 32)
    const int half  = wave & 1;          // code half
    const int g     = lane >> 4;         // quad
    const int c     = lane & 15;
    const int tok0  = blockIdx.x * TOKPB;

    // ---- init: residual = x, into LDS (4 threads per token) ----
    {
        const int t = tid >> 2, part = tid & 3;
        const float4* xp = (const float4*)(x + (size_t)(tok0 + t) * D + part * 16);
        float4* rr = (float4*)(lds_resid + t * 68 + part * 16);
        #pragma unroll
        for (int k2 = 0; k2 < 4; ++k2) rr[k2] = xp[k2];
    }

    // ---- chunk-staging DMA: 16 KB planes (512 thr x 2 x 16B) + 256 B csqh ----
    const float* ws_csqh = ws_csq + 8192;
    auto issue_chunk = [&](int step, int b) {
        const int4* src = ws_cb + (size_t)step * 1024 + tid;
        LDS_AS char* ldst = (LDS_AS char*)(&lds_stage[b][0]) + tid * 16;
        __builtin_amdgcn_global_load_lds((const GLOBAL_AS unsigned int*)src,
                                         (LDS_AS unsigned int*)ldst, 16, 0, 0);
        __builtin_amdgcn_global_load_lds((const GLOBAL_AS unsigned int*)(src + 512),
                                         (LDS_AS unsigned int*)(ldst + 512 * 16), 16, 0, 0);
        if (tid < 16) {
            const int4* cs = (const int4*)(ws_csqh + (size_t)step * 64) + tid;
            LDS_AS unsigned* cdst =
                (LDS_AS unsigned*)((LDS_AS char*)(&lds_stage[b][1024]) + tid * 16);
            __builtin_amdgcn_global_load_lds((const GLOBAL_AS unsigned int*)cs, cdst, 16, 0, 0);
        }
    };

    issue_chunk(0, 0);       // preload (q=0, ch=0) into buffer 0
    int pbuf = 0;

    for (int q = 0; q < NQ; ++q) {
        __syncthreads();     // residual init / previous q's update visible

        // ---- A-split for the group's two 16-token sub-tiles ----
        short8 ah0[2], ah1[2], al0[2], al1[2];
        #pragma unroll
        for (int s = 0; s < 2; ++s) {
            const float* rr = lds_resid + (group * 32 + s * 16 + c) * 68;
            float4 f0 = *(const float4*)(rr + 8 * g);
            float4 f1 = *(const float4*)(rr + 8 * g + 4);
            float4 f2 = *(const float4*)(rr + 32 + 8 * g);
            float4 f3 = *(const float4*)(rr + 36 + 8 * g);
            const float* v0 = (const float*)&f0;
            const float* v1 = (const float*)&f1;
            const float* v2 = (const float*)&f2;
            const float* v3 = (const float*)&f3;
            #pragma unroll
            for (int j = 0; j < 4; ++j) {
                float a = v0[j], b = v1[j], e = v2[j], f = v3[j];
                unsigned ha = bf16_rne_bits(a);
                unsigned hb = bf16_rne_bits(b);
                unsigned he = bf16_rne_bits(e);
                unsigned hf = bf16_rne_bits(f);
                ah0[s][j]   = (short)ha;  ah0[s][4+j] = (short)hb;
                ah1[s][j]   = (short)he;  ah1[s][4+j] = (short)hf;
                al0[s][j]   = (short)bf16_rne_bits(a - __uint_as_float(ha << 16));
                al0[s][4+j] = (short)bf16_rne_bits(b - __uint_as_float(hb << 16));
                al1[s][j]   = (short)bf16_rne_bits(e - __uint_as_float(he << 16));
                al1[s][4+j] = (short)bf16_rne_bits(f - __uint_as_float(hf << 16));
            }
        }

        // packed top-3 per (sub-tile, row) — ascending u32
        unsigned T1[2][4], T2[2][4], T3[2][4];
        #pragma unroll
        for (int s = 0; s < 2; ++s)
            #pragma unroll
            for (int r = 0; r < 4; ++r) { T1[s][r] = 0xFFFFFFFFu; T2[s][r] = 0xFFFFFFFFu; T3[s][r] = 0xFFFFFFFFu; }

        for (int ch = 0; ch < NCHUNK; ++ch) {
            // barrier: (a) all waves done reading buf[pbuf^1] (safe to overwrite),
            // (b) drains pbuf's DMA — issued one full compute-phase ago, so cheap.
            __syncthreads();
            const int nstep = q * NCHUNK + ch + 1;
            if (nstep < NQ * NCHUNK) issue_chunk(nstep, pbuf ^ 1);   // overlaps compute below

            const char*  bp   = (const char*)&lds_stage[pbuf][0] + (c << 4) + (g << 10) + half * 512;
            const float* csqb = (const float*)&lds_stage[pbuf][1024];

            #pragma unroll
            for (int i = 0; i < 2; ++i) {        // this half's two 16-code tiles
                short8 bh0 = *(const short8*)(bp + i * 256);
                short8 bh1 = *(const short8*)(bp + 4096  + i * 256);
                short8 bl0 = *(const short8*)(bp + 8192  + i * 256);
                short8 bl1 = *(const short8*)(bp + 12288 + i * 256);
                const float sd = csqb[(half * 2 + i) * 16 + c];
                const unsigned codev = (unsigned)(ch * CHUNK + (half * 2 + i) * 16 + c);
                #pragma unroll
                for (int s = 0; s < 2; ++s) {
                    f32x4 acc = {sd, sd, sd, sd};
                    acc = __builtin_amdgcn_mfma_f32_16x16x32_bf16(ah0[s], bh0, acc, 0, 0, 0);
                    acc = __builtin_amdgcn_mfma_f32_16x16x32_bf16(ah1[s], bh1, acc, 0, 0, 0);
                    acc = __builtin_amdgcn_mfma_f32_16x16x32_bf16(al0[s], bh0, acc, 0, 0, 0);
                    acc = __builtin_amdgcn_mfma_f32_16x16x32_bf16(ah0[s], bl0, acc, 0, 0, 0);
                    acc = __builtin_amdgcn_mfma_f32_16x16x32_bf16(al1[s], bh1, acc, 0, 0, 0);
                    acc = __builtin_amdgcn_mfma_f32_16x16x32_bf16(ah1[s], bl1, acc, 0, 0, 0);
                    #pragma unroll
                    for (int r = 0; r < 4; ++r) {
                        unsigned p = (__float_as_uint(acc[r]) & 0xFFFFFC00u) | codev;
                        unsigned n2 = umn(T2[s][r], umx(T1[s][r], p));
                        unsigned n3 = umn(T3[s][r], umx(T2[s][r], p));
                        T1[s][r] = umn(T1[s][r], p);
                        T2[s][r] = n2;
                        T3[s][r] = n3;
                    }
                }
            }
            pbuf ^= 1;
        }

        // ---- cross-lane top-3 merge over the 16 c-lanes ----
        #pragma unroll
        for (int st = 1; st <= 8; st <<= 1) {
            #pragma unroll
            for (int s = 0; s < 2; ++s) {
                #pragma unroll
                for (int r = 0; r < 4; ++r) {
                    unsigned o1 = (unsigned)__shfl_xor((int)T1[s][r], st);
                    unsigned o2 = (unsigned)__shfl_xor((int)T2[s][r], st);
                    unsigned o3 = (unsigned)__shfl_xor((int)T3[s][r], st);
                    unsigned x1 = umn(T1[s][r], o1), y1 = umx(T1[s][r], o1);
                    unsigned x2 = umn(T2[s][r], o2), y2 = umx(T2[s][r], o2);
                    unsigned x3 = umn(T3[s][r], o3);
                    T1[s][r] = x1;
                    T3[s][r] = umed3(y1, x2, umn(y2, x3));
                    T2[s][r] = umn(y1, x2);
                }
            }
        }

        // ---- publish per-half candidates ----
        if (c == 0) {
            #pragma unroll
            for (int s = 0; s < 2; ++s)
                #pragma unroll
                for (int r = 0; r < 4; ++r) {
                    const int idx = (group * 32 + s * 16 + g * 4 + r) * 3;
                    lds_cand[half][idx + 0] = T1[s][r];
                    lds_cand[half][idx + 1] = T2[s][r];
                    lds_cand[half][idx + 2] = T3[s][r];
                }
        }
        __syncthreads();

        // ---- cross-half merge + ALWAYS-ON exact refinement (each wave: 16 tokens) ----
        {
            const int t4  = lane >> 2;          // token within sub-tile
            const int sel = lane & 3;           // candidate slot (3 duplicates slot 2)
            const int row = group * 32 + half * 16 + t4;
            unsigned a1 = lds_cand[0][row * 3 + 0];
            unsigned a2 = lds_cand[0][row * 3 + 1];
            unsigned a3 = lds_cand[0][row * 3 + 2];
            unsigned b1 = lds_cand[1][row * 3 + 0];
            unsigned b2 = lds_cand[1][row * 3 + 1];
            unsigned b3 = lds_cand[1][row * 3 + 2];
            unsigned x1 = umn(a1, b1), y1 = umx(a1, b1);
            unsigned x2 = umn(a2, b2), y2 = umx(a2, b2);
            unsigned x3 = umn(a3, b3);
            unsigned m1 = x1;
            unsigned m2 = umn(y1, x2);
            unsigned m3 = umed3(y1, x2, umn(y2, x3));
            const unsigned psel = (sel == 0) ? m1 : ((sel == 1) ? m2 : m3);
            const int cd = (int)(psel & 1023u);

            // exact fp32 distance, bit-identical comparator arithmetic to rounds 3..9
            const float4* rrv = (const float4*)(lds_resid + row * 68);
            const float4* cpv = (const float4*)(cb + ((size_t)(q * KCODES + cd)) * D);
            float ax = 0.f, ay = 0.f, az = 0.f, aw = 0.f;
            #pragma unroll
            for (int j = 0; j < 16; ++j) {
                float4 rv = rrv[j];
                float4 cv = cpv[j];
                ax = fmaf(rv.x, cv.x, ax);
                ay = fmaf(rv.y, cv.y, ay);
                az = fmaf(rv.z, cv.z, az);
                aw = fmaf(rv.w, cv.w, aw);
            }
            float dot = (ax + ay) + (az + aw);
            float dd = fmaf(dot, -2.0f, ws_csq[q * KCODES + cd]);

            const int base = lane & ~3;
            float d0 = __shfl(dd, base);
            float d1 = __shfl(dd, base + 1);
            float d2 = __shfl(dd, base + 2);
            int cc0 = (int)(m1 & 1023u);
            int cc1 = (int)(m2 & 1023u);
            int cc2 = (int)(m3 & 1023u);
            float db = d0; int pick = cc0;
            if (d1 < db || (d1 == db && cc1 < pick)) { db = d1; pick = cc1; }
            if (d2 < db || (d2 == db && cc2 < pick)) { db = d2; pick = cc2; }
            if (sel == 0) lds_pick[row] = pick;
        }
        __syncthreads();

        // ---- residual update in LDS: resid -= cb[q][ifin] (4 threads per token) ----
        {
            const int t = tid >> 2, part = tid & 3;
            const int ifin = lds_pick[t];
            const float4* cp = (const float4*)(cb + ((size_t)(q * KCODES + ifin)) * D + part * 16);
            float4* rr = (float4*)(lds_resid + t * 68 + part * 16);
            #pragma unroll
            for (int k2 = 0; k2 < 4; ++k2) {
                float4 rv = rr[k2], cv = cp[k2];
                rv.x -= cv.x; rv.y -= cv.y; rv.z -= cv.z; rv.w -= cv.w;
                rr[k2] = rv;
            }
        }
    }

    // ---- epilogue: out = x - residual_final (4 threads per token) ----
    __syncthreads();
    {
        const int t = tid >> 2, part = tid & 3;
        const float4* xp = (const float4*)(x + (size_t)(tok0 + t) * D + part * 16);
        const float4* rr = (const float4*)(lds_resid + t * 68 + part * 16);
        float4* op = (float4*)(out + (size_t)(tok0 + t) * D + part * 16);
        #pragma unroll
        for (int k2 = 0; k2 < 4; ++k2) {
            float4 xv = xp[k2], rv = rr[k2];
            float4 o;
            o.x = xv.x - rv.x; o.y = xv.y - rv.y;
            o.z = xv.z - rv.z; o.w = xv.w - rv.w;
            op[k2] = o;
        }
    }
}

extern "C" void kernel_launch(void* const* d_in, const int* in_sizes, int n_in,
                              void* d_out, int out_size, void* d_ws, size_t ws_size,
                              hipStream_t stream) {
    const float* x  = (const float*)d_in[0];
    const float* cb = (const float*)d_in[1];
    float* out = (float*)d_out;

    int4*  ws_cb   = (int4*)d_ws;                                      // 2 MB
    float* ws_csq  = (float*)((char*)d_ws + (size_t)2 * 1024 * 1024);  // 32 KB exact
    float* ws_csqh = ws_csq + 8192;                                    // 32 KB seed (= ws_csq+8192)

    prep_cb <<<512, 256, 0, stream>>>(cb, ws_cb);
    prep_csq<<< 32, 256, 0, stream>>>(cb, ws_csq, ws_csqh);

    const int n_tokens = in_sizes[0] / D;            // 65536
    const int grid = n_tokens / TOKPB;               // 512 blocks = 2/CU, exactly resident
    rvq_mfma<<<grid, TPB, 0, stream>>>(x, cb, ws_cb, ws_csq, out);
}